// Round 5
// baseline (94.842 us; speedup 1.0000x reference)
//
#include <hip/hip_runtime.h>
#include <math.h>

#define H 2048
#define W 2048
#define K 16
#define P 15
#define WP 2052        // win pitch: W + 4 replicated guard cols (wrapped float4 reads)
#define LDSP 272       // LDS pitch: 256 tile cols + 16 halo cols
#define TR 16          // tile rows per win block

typedef float v4 __attribute__((ext_vector_type(4)));
typedef v4 uv4 __attribute__((aligned(4)));   // dword-aligned vector load

// ---- kernel 1: fused 15x15 exclusive box-sum img -> win, LDS-staged ----
// Block = 16-row x 256-col tile; 1024 blocks (XCD row-banded), 320 threads,
// 33.7 KB LDS -> 4 blocks/CU (20 waves/CU). Block 0 also computes C + offsets.
__global__ __launch_bounds__(320) void geneo_win(
        const float* __restrict__ img,
        float* __restrict__ win,
        const float* __restrict__ patterns,
        const float* __restrict__ vectors,
        float* __restrict__ consts,
        int* __restrict__ offs) {
    // slot s (s=0..30) holds img row r0-15+s; the vertical walk overwrites
    // slot ii with colsum row r0+ii (slot ii's img row is dead at that point).
    __shared__ float sl[31][LDSP];   // 33,728 B
    __shared__ float psum[5];
    int t = threadIdx.x;

    // XCD row-band swizzle (round-robin d%8): XCD x produces win rows
    // [256x, 256x+256) -- matches gather's consumer band; halo rows shared
    // between adjacent row-tiles on the same XCD hit its L2.
    int d   = blockIdx.x;
    int m   = d >> 3;                               // [0,128)
    int r0  = ((d & 7) << 8) | ((m & 15) << 4);     // 16-row tile
    int c0  = (m >> 4) << 8;                        // 256-col tile

    // --- consts (block 0 only) ---
    if (d == 0) {
        float ps = 0.f;
        for (int idx = t; idx < 900; idx += 320) {  // 900 v4 = 3600 floats
            v4 v = *(const v4*)&patterns[idx * 4];
            ps += (v.x + v.y) + (v.z + v.w);
        }
        #pragma unroll
        for (int q = 32; q > 0; q >>= 1) ps += __shfl_down(ps, q, 64);
        if ((t & 63) == 0) psum[t >> 6] = ps;
        if (t < 2 * K) offs[t] = (int)floorf(vectors[t]);
        __syncthreads();
        if (t == 0) {
            float total = ((psum[0] + psum[1]) + (psum[2] + psum[3])) + psum[4];
            consts[0] = (16.0f - total * (1.0f / 225.0f)) * (1.0f / 15.0f);
        }
    }

    // --- stage img rows [r0-15, r0+16) x cols [c0-16, c0+256) into LDS ---
    // 31 rows x 68 v4 = 2108 independent float4 loads, ~7/thread (deep burst).
    for (int idx = t; idx < 31 * 68; idx += 320) {
        int q = idx / 68;                 // 0..30 -> img row r0-15+q -> slot q
        int c = idx - q * 68;             // v4 col group
        int grow = r0 - 15 + q;
        int gcol = c0 - 16 + 4 * c;
        v4 v = {0.f, 0.f, 0.f, 0.f};
        if (grow >= 0 && gcol >= 0)       // zero-pad (gcol<0 => whole v4 < 0)
            v = *(const v4*)&img[grow * W + gcol];
        *(v4*)&sl[q][4 * c] = v;
    }
    __syncthreads();

    // --- vertical running sum in LDS (one column/thread, stride-1 lanes) ---
    if (t < LDSP) {
        float s = 0.f;
        #pragma unroll
        for (int q = 0; q < 15; ++q) s += sl[q][t];      // rows r0-15..r0-1
        #pragma unroll
        for (int ii = 0; ii < TR; ++ii) {
            float sv = s;
            s += sl[ii + 15][t] - sl[ii][t];             // +row r0+ii, -row r0+ii-15
            sl[ii][t] = sv;                              // colsum row r0+ii
        }
    }
    __syncthreads();

    // --- horizontal 15-tap (one output column/thread, stride-1 lanes) ---
    if (t < 256) {
        int gj = c0 + t;                  // window = lds cols t+1 .. t+15
        #pragma unroll 4
        for (int ii = 0; ii < TR; ++ii) {
            float s = 0.f;
            #pragma unroll
            for (int mm = 1; mm <= 15; ++mm) s += sl[ii][t + mm];
            int gi = r0 + ii;
            win[gi * WP + gj] = s;
            if (c0 == 0 && t < 4)         // guard cols 2048..2051 = cols 0..3
                win[gi * WP + 2048 + t] = s;
        }
    }
}

// ---- kernel 2: 16-way circular-shift gather-sum, XCD-banded, 8 out/thread ----
__global__ __launch_bounds__(256) void geneo_gather(
        const float* __restrict__ win,
        const float* __restrict__ consts,
        const int* __restrict__ offs,
        float* __restrict__ out) {
    __shared__ int soy[K], sox[K];
    __shared__ float sC;
    int t = threadIdx.x;
    if (t < K) { soy[t] = offs[t * 2]; sox[t] = offs[t * 2 + 1]; }
    if (t == 0) sC = consts[0];
    __syncthreads();

    // round-robin d%8 XCD assignment: XCD x gets rows [x*256, x*256+256)
    // -> its win band (~2.1 MB) fits the 4 MiB per-XCD L2 (15/16 reads hit L2)
    int d = blockIdx.x;              // 2048 blocks, one output row each
    int i = ((d & 7) << 8) | (d >> 3);
    int j = 4 * t;                   // cols j and j+1024 per thread

    const float S = 1.0f / 3375.0f;  // 1/(p^2 (K-1)), data-independent
    v4 acc0 = {0.f, 0.f, 0.f, 0.f};
    v4 acc1 = {0.f, 0.f, 0.f, 0.f};
    #pragma unroll
    for (int k = 0; k < K; ++k) {
        int ri = (i - soy[k]) & (H - 1);
        int rj = (j - sox[k]) & (W - 1);
        const float* row = &win[ri * WP];
        acc0 += *(const uv4*)&row[rj];
        acc1 += *(const uv4*)&row[rj ^ 1024];   // (rj+1024) mod 2048
    }
    v4 o0 = acc0 * S + sC;
    v4 o1 = acc1 * S + sC;
    *(v4*)&out[i * W + j]        = o0;
    *(v4*)&out[i * W + j + 1024] = o1;
}

extern "C" void kernel_launch(void* const* d_in, const int* in_sizes, int n_in,
                              void* d_out, int out_size, void* d_ws, size_t ws_size,
                              hipStream_t stream) {
    const float* x        = (const float*)d_in[0]; // (1,1,H,W)
    const float* patterns = (const float*)d_in[1]; // (K,P,P)
    const float* vectors  = (const float*)d_in[2]; // (K,2)
    float* out = (float*)d_out;

    float* win    = (float*)d_ws;          // H*WP floats
    float* consts = win + H * WP;          // 1 float
    int*   offs   = (int*)(consts + 1);    // 2K ints (oy,ox pairs)

    geneo_win<<<1024, 320, 0, stream>>>(x, win, patterns, vectors, consts, offs);
    geneo_gather<<<2048, 256, 0, stream>>>(win, consts, offs, out);
}